// Round 1
// baseline (1116.325 us; speedup 1.0000x reference)
//
#include <hip/hip_runtime.h>
#include <hip/hip_bf16.h>
#include <float.h>

#define N_ROWS 16384
#define DIM 256
#define NE 8192
#define DECAY 0.8f
#define OMD 0.2f
#define EPS 1e-5f

// ---- ws layout (float element offsets) ----
#define WS_EMBEDT 0            // 8192*256
#define WS_ESUMT  2097152      // 8192*256
#define WS_ENORM  4194304      // 8192
#define WS_COUNTS 4202496      // 8192
#define WS_SMOOTH 4210688      // 8192
#define WS_PV     4218880      // 16384*4
#define WS_PI     4284416      // 16384*4 (int)
#define WS_INDI   4349952      // 16384 (int)
#define WS_LOSS   4366336      // 1
#define WS_TOTAL  4366337      // 1

// ---- out layout (float element offsets) ----
#define OUT_Q    0
#define OUT_IND  4194304
#define OUT_LOSS 4210688
#define OUT_NE   4210689
#define OUT_NCS  6307841
#define OUT_NEA  6316033

#define BM 64
#define BN 64
#define KB 16
#define PANELW 2048

__global__ void enorm_kernel(const float* __restrict__ embed, float* __restrict__ enorm) {
    int c = blockIdx.x * 256 + threadIdx.x;
    float s = 0.f;
    for (int d = 0; d < DIM; ++d) { float v = embed[d * NE + c]; s += v * v; }
    enorm[c] = s;
}

// embed [DIM][NE] -> embedT [NE][DIM]
__global__ __launch_bounds__(256) void transpose_kernel(const float* __restrict__ embed,
                                                        float* __restrict__ embedT) {
    __shared__ float t[32][33];
    int c0 = blockIdx.x * 32, d0 = blockIdx.y * 32;
    int tx = threadIdx.x & 31, ty = threadIdx.x >> 5;  // 32 x 8
    #pragma unroll
    for (int r = 0; r < 4; ++r)
        t[ty + r * 8][tx] = embed[(d0 + ty + r * 8) * NE + c0 + tx];  // t[d_local][c_local]
    __syncthreads();
    #pragma unroll
    for (int r = 0; r < 4; ++r)
        embedT[(c0 + ty + r * 8) * DIM + d0 + tx] = t[tx][ty + r * 8];
}

// fused  s(n,c) = ||e_c||^2 - 2 x_n . e_c  with running argmin per row
__global__ __launch_bounds__(256) void argmin_kernel(
    const float* __restrict__ x, const float* __restrict__ embed,
    const float* __restrict__ enorm, float* __restrict__ pv, int* __restrict__ pi) {
    __shared__ float As[KB][BM + 4];
    __shared__ float Bs[KB][BN + 4];
    __shared__ float rv[BM][17];
    __shared__ int   ri[BM][17];
    const int tid = threadIdx.x;
    const int tx = tid & 15, ty = tid >> 4;
    const int row0 = blockIdx.x * BM;
    const int cbase = blockIdx.y * PANELW;
    const int am = tid >> 2, ak = (tid & 3) * 4;   // A staging: row, k
    const int bk = tid >> 4, bn = (tid & 15) * 4;  // B staging: k, col

    float bestv[4] = {FLT_MAX, FLT_MAX, FLT_MAX, FLT_MAX};
    int   besti[4] = {0, 0, 0, 0};

    for (int cc = 0; cc < PANELW; cc += BN) {
        const int c0 = cbase + cc;
        float acc[4][4] = {};
        for (int k0 = 0; k0 < DIM; k0 += KB) {
            float4 av = *(const float4*)&x[(row0 + am) * DIM + k0 + ak];
            As[ak + 0][am] = av.x; As[ak + 1][am] = av.y;
            As[ak + 2][am] = av.z; As[ak + 3][am] = av.w;
            float4 bv = *(const float4*)&embed[(k0 + bk) * NE + c0 + bn];
            *(float4*)&Bs[bk][bn] = bv;
            __syncthreads();
            #pragma unroll
            for (int k = 0; k < KB; ++k) {
                float4 afv = *(const float4*)&As[k][ty * 4];
                float4 bfv = *(const float4*)&Bs[k][tx * 4];
                float ar[4] = {afv.x, afv.y, afv.z, afv.w};
                float br[4] = {bfv.x, bfv.y, bfv.z, bfv.w};
                #pragma unroll
                for (int i = 0; i < 4; ++i)
                    #pragma unroll
                    for (int j = 0; j < 4; ++j)
                        acc[i][j] += ar[i] * br[j];
            }
            __syncthreads();
        }
        #pragma unroll
        for (int j = 0; j < 4; ++j) {
            const int c = c0 + tx * 4 + j;
            const float en = enorm[c];
            #pragma unroll
            for (int i = 0; i < 4; ++i) {
                float s = en - 2.f * acc[i][j];
                if (s < bestv[i]) { bestv[i] = s; besti[i] = c; }
            }
        }
    }
    #pragma unroll
    for (int i = 0; i < 4; ++i) { rv[ty * 4 + i][tx] = bestv[i]; ri[ty * 4 + i][tx] = besti[i]; }
    __syncthreads();
    if (tid < BM) {
        float bv = rv[tid][0]; int bi = ri[tid][0];
        for (int t = 1; t < 16; ++t) {
            float v = rv[tid][t]; int ii = ri[tid][t];
            if (v < bv || (v == bv && ii < bi)) { bv = v; bi = ii; }
        }
        pv[(row0 + tid) * 4 + blockIdx.y] = bv;
        pi[(row0 + tid) * 4 + blockIdx.y] = bi;
    }
}

__global__ void merge_kernel(const float* __restrict__ pv, const int* __restrict__ pi,
                             float* __restrict__ out_ind, int* __restrict__ ind_i) {
    int r = blockIdx.x * 256 + threadIdx.x;
    float bv = pv[r * 4]; int bi = pi[r * 4];
    #pragma unroll
    for (int p = 1; p < 4; ++p) {
        float v = pv[r * 4 + p]; int ii = pi[r * 4 + p];
        if (v < bv || (v == bv && ii < bi)) { bv = v; bi = ii; }
    }
    out_ind[r] = (float)bi;
    ind_i[r] = bi;
}

// one wave per row: quantize gather, commit-loss partial, counts, embed_sum scatter
__global__ __launch_bounds__(256) void gather_kernel(
    const float* __restrict__ x, const float* __restrict__ embedT,
    const int* __restrict__ ind, float* __restrict__ q_out,
    float* __restrict__ esumT, float* __restrict__ counts, float* __restrict__ loss_acc) {
    const int row = blockIdx.x * 4 + (threadIdx.x >> 6);
    const int lane = threadIdx.x & 63;
    const int idx = ind[row];
    float4 e  = *(const float4*)&embedT[idx * DIM + lane * 4];
    float4 xv = *(const float4*)&x[row * DIM + lane * 4];
    *(float4*)&q_out[row * DIM + lane * 4] = e;
    float dx = e.x - xv.x, dy = e.y - xv.y, dz = e.z - xv.z, dw = e.w - xv.w;
    float s = dx * dx + dy * dy + dz * dz + dw * dw;
    #pragma unroll
    for (int off = 32; off; off >>= 1) s += __shfl_down(s, off);
    __shared__ float ls[4];
    if (lane == 0) { ls[threadIdx.x >> 6] = s; atomicAdd(&counts[idx], 1.0f); }
    atomicAdd(&esumT[idx * DIM + lane * 4 + 0], xv.x);
    atomicAdd(&esumT[idx * DIM + lane * 4 + 1], xv.y);
    atomicAdd(&esumT[idx * DIM + lane * 4 + 2], xv.z);
    atomicAdd(&esumT[idx * DIM + lane * 4 + 3], xv.w);
    __syncthreads();
    if (threadIdx.x == 0) atomicAdd(loss_acc, ls[0] + ls[1] + ls[2] + ls[3]);
}

__global__ void ncs_kernel(const float* __restrict__ cs, const float* __restrict__ counts,
                           float* __restrict__ out_ncs, float* __restrict__ total) {
    int c = blockIdx.x * 256 + threadIdx.x;
    float v = cs[c] * DECAY + counts[c] * OMD;
    out_ncs[c] = v;
    float s = v;
    #pragma unroll
    for (int off = 32; off; off >>= 1) s += __shfl_down(s, off);
    __shared__ float bs[4];
    if ((threadIdx.x & 63) == 0) bs[threadIdx.x >> 6] = s;
    __syncthreads();
    if (threadIdx.x == 0) atomicAdd(total, bs[0] + bs[1] + bs[2] + bs[3]);
}

__global__ void smooth_kernel(const float* __restrict__ out_ncs, const float* __restrict__ total,
                              float* __restrict__ smoothed, const float* __restrict__ loss_acc,
                              float* __restrict__ out_loss) {
    int c = blockIdx.x * 256 + threadIdx.x;
    float tot = *total;
    float v = out_ncs[c];
    smoothed[c] = (v + EPS) / (tot + (float)NE * EPS) * tot;
    if (blockIdx.x == 0 && threadIdx.x == 0)
        *out_loss = *loss_acc * (1.0f / ((float)N_ROWS * (float)DIM));
}

// new_embed_avg / new_embed, transposing esumT back to [DIM][NE]
__global__ __launch_bounds__(256) void final_kernel(
    const float* __restrict__ embed_avg, const float* __restrict__ esumT,
    const float* __restrict__ smoothed, float* __restrict__ out_ne,
    float* __restrict__ out_nea) {
    __shared__ float t[32][33];
    int c0 = blockIdx.x * 32, d0 = blockIdx.y * 32;
    int tx = threadIdx.x & 31, ty = threadIdx.x >> 5;
    #pragma unroll
    for (int r = 0; r < 4; ++r)
        t[ty + r * 8][tx] = esumT[(c0 + ty + r * 8) * DIM + d0 + tx];  // t[c_local][d_local]
    __syncthreads();
    #pragma unroll
    for (int r = 0; r < 4; ++r) {
        int d = d0 + ty + r * 8, c = c0 + tx;
        float es = t[tx][ty + r * 8];
        float ea = embed_avg[d * NE + c] * DECAY + es * OMD;
        out_nea[d * NE + c] = ea;
        out_ne[d * NE + c] = ea / smoothed[c];
    }
}

extern "C" void kernel_launch(void* const* d_in, const int* in_sizes, int n_in,
                              void* d_out, int out_size, void* d_ws, size_t ws_size,
                              hipStream_t stream) {
    const float* input     = (const float*)d_in[0];
    const float* embed     = (const float*)d_in[1];
    const float* cs        = (const float*)d_in[2];
    const float* embed_avg = (const float*)d_in[3];
    float* out = (float*)d_out;
    float* ws  = (float*)d_ws;

    hipMemsetAsync(ws + WS_ESUMT, 0, (size_t)2097152 * 4, stream);
    hipMemsetAsync(ws + WS_COUNTS, 0, (size_t)8192 * 4, stream);
    hipMemsetAsync(ws + WS_LOSS, 0, (size_t)2 * 4, stream);

    enorm_kernel<<<32, 256, 0, stream>>>(embed, ws + WS_ENORM);
    transpose_kernel<<<dim3(256, 8), 256, 0, stream>>>(embed, ws + WS_EMBEDT);
    argmin_kernel<<<dim3(256, 4), 256, 0, stream>>>(input, embed, ws + WS_ENORM,
                                                    ws + WS_PV, (int*)(ws + WS_PI));
    merge_kernel<<<64, 256, 0, stream>>>(ws + WS_PV, (int*)(ws + WS_PI),
                                         out + OUT_IND, (int*)(ws + WS_INDI));
    gather_kernel<<<4096, 256, 0, stream>>>(input, ws + WS_EMBEDT, (int*)(ws + WS_INDI),
                                            out + OUT_Q, ws + WS_ESUMT,
                                            ws + WS_COUNTS, ws + WS_LOSS);
    ncs_kernel<<<32, 256, 0, stream>>>(cs, ws + WS_COUNTS, out + OUT_NCS, ws + WS_TOTAL);
    smooth_kernel<<<32, 256, 0, stream>>>(out + OUT_NCS, ws + WS_TOTAL, ws + WS_SMOOTH,
                                          ws + WS_LOSS, out + OUT_LOSS);
    final_kernel<<<dim3(256, 8), 256, 0, stream>>>(embed_avg, ws + WS_ESUMT, ws + WS_SMOOTH,
                                                   out + OUT_NE, out + OUT_NEA);
}

// Round 3
// 399.030 us; speedup vs baseline: 2.7976x; 2.7976x over previous
//
#include <hip/hip_runtime.h>
#include <hip/hip_bf16.h>
#include <float.h>
#include <stdint.h>

#define N_ROWS 16384
#define DIM 256
#define NE 8192
#define K2 768
#define DECAY 0.8f
#define OMD 0.2f
#define EPS 1e-5f
#define NPAN 8
#define PANELC 1024

// ---- ws layout (float element offsets) ----
#define WS_X2     0            // 16384*768 bf16 (6291456 floats)
#define WS_EMBEDT 0            // overlay (after argmin): 8192*256 f32
#define WS_ESUMT  2097152      // overlay (after argmin): 8192*256 f32
#define WS_B2T    6291456      // 8192*768 bf16 (3145728 floats)
#define WS_ENORM  9437184      // 8192
#define WS_COUNTS 9445376      // 8192
#define WS_SMOOTH 9453568      // 8192
#define WS_PV     9461760      // 16384*8
#define WS_PI     9592832      // 16384*8 (int)
#define WS_INDI   9723904      // 16384 (int)
#define WS_LOSS   9740288      // 1
#define WS_TOTAL  9740289      // 1

// ---- out layout (float element offsets) ----
#define OUT_Q    0
#define OUT_IND  4194304
#define OUT_LOSS 4210688
#define OUT_NE   4210689
#define OUT_NCS  6307841
#define OUT_NEA  6316033

typedef __attribute__((ext_vector_type(8))) short bf16x8;
typedef __attribute__((ext_vector_type(4))) float f32x4;

static __device__ __forceinline__ ushort f2bf(float f) {
    uint32_t u = __float_as_uint(f);
    uint32_t r = (u + 0x7fffu + ((u >> 16) & 1u)) >> 16;
    return (ushort)r;
}
static __device__ __forceinline__ float bf2f(ushort h) {
    return __uint_as_float(((uint32_t)h) << 16);
}
static __device__ __forceinline__ void async16(void* lds, const void* g) {
    __builtin_amdgcn_global_load_lds(
        (const __attribute__((address_space(1))) uint32_t*)g,
        (__attribute__((address_space(3))) uint32_t*)lds, 16, 0, 0);
}

// x [16384][256] f32 -> X2 [16384][768] bf16 = [hi | lo | hi]
__global__ __launch_bounds__(256) void convx_kernel(const float* __restrict__ x,
                                                    ushort* __restrict__ X2) {
    int i = blockIdx.x * 256 + threadIdx.x;
    int row = i >> 6, q = (i & 63) * 4;
    float4 v = *(const float4*)&x[(size_t)row * 256 + q];
    ushort4 hi, lo;
    hi.x = f2bf(v.x); hi.y = f2bf(v.y); hi.z = f2bf(v.z); hi.w = f2bf(v.w);
    lo.x = f2bf(v.x - bf2f(hi.x)); lo.y = f2bf(v.y - bf2f(hi.y));
    lo.z = f2bf(v.z - bf2f(hi.z)); lo.w = f2bf(v.w - bf2f(hi.w));
    *(ushort4*)&X2[(size_t)row * K2 + q]       = hi;
    *(ushort4*)&X2[(size_t)row * K2 + 256 + q] = lo;
    *(ushort4*)&X2[(size_t)row * K2 + 512 + q] = hi;
}

// embed [256][8192] f32 -> B2T [8192][768] bf16 = [hi | hi | lo] per col
__global__ __launch_bounds__(256) void convE_kernel(const float* __restrict__ embed,
                                                    ushort* __restrict__ B2T) {
    __shared__ float t[32][33];
    int c0 = blockIdx.x * 32, d0 = blockIdx.y * 32;
    int tx = threadIdx.x & 31, ty = threadIdx.x >> 5;
    #pragma unroll
    for (int r = 0; r < 4; ++r)
        t[ty + r * 8][tx] = embed[(size_t)(d0 + ty + r * 8) * NE + c0 + tx];
    __syncthreads();
    #pragma unroll
    for (int r = 0; r < 4; ++r) {
        int c = c0 + ty + r * 8, d = d0 + tx;
        float v = t[tx][ty + r * 8];
        ushort hi = f2bf(v);
        ushort lo = f2bf(v - bf2f(hi));
        B2T[(size_t)c * K2 + d]       = hi;
        B2T[(size_t)c * K2 + 256 + d] = hi;
        B2T[(size_t)c * K2 + 512 + d] = lo;
    }
}

__global__ void enorm_kernel(const float* __restrict__ embed, float* __restrict__ enorm) {
    int c = blockIdx.x * 256 + threadIdx.x;
    float s = 0.f;
    for (int d = 0; d < DIM; ++d) { float v = embed[(size_t)d * NE + c]; s += v * v; }
    enorm[c] = s;
}

// embed [DIM][NE] -> embedT [NE][DIM]  (f32, for exact rerank + quantize gather)
__global__ __launch_bounds__(256) void transpose_kernel(const float* __restrict__ embed,
                                                        float* __restrict__ embedT) {
    __shared__ float t[32][33];
    int c0 = blockIdx.x * 32, d0 = blockIdx.y * 32;
    int tx = threadIdx.x & 31, ty = threadIdx.x >> 5;
    #pragma unroll
    for (int r = 0; r < 4; ++r)
        t[ty + r * 8][tx] = embed[(size_t)(d0 + ty + r * 8) * NE + c0 + tx];
    __syncthreads();
    #pragma unroll
    for (int r = 0; r < 4; ++r)
        embedT[(size_t)(c0 + ty + r * 8) * DIM + d0 + tx] = t[tx][ty + r * 8];
}

// MFMA distance GEMM + fused per-panel argmin.  score(n,c) = ||e_c||^2 - 2 x_n . e_c
__global__ __launch_bounds__(256) void argmin_mfma(
    const ushort* __restrict__ X2, const ushort* __restrict__ B2T,
    const float* __restrict__ enorm, float* __restrict__ pv, int* __restrict__ pi) {
    __shared__ ushort smem[16384];           // 32 KB: As 16KB | Bs 16KB
    ushort* As = smem;
    ushort* Bs = smem + 8192;
    const int tid = threadIdx.x;
    const int lane = tid & 63;
    const int wid = tid >> 6;
    const int fl = lane & 15, fh = lane >> 4;
    const int wr0 = (wid >> 1) * 64, wc0 = (wid & 1) * 64;
    const int row0 = blockIdx.x * 128;
    const int cpan = blockIdx.y * PANELC;

    // staging map: LDS slot S = tid + j*256 (16B units); row = S/8, k-slot = S%8
    // source pre-swizzled: global k-slot = (S%8) ^ (row&7)  => LDS[row][s] = G[row][s^(row&7)]
    const int srow = tid >> 3;
    const int skq = (tid & 7) ^ (srow & 7);
    const ushort* aSrc[4];
    ushort* aDst[4];
    ushort* bDst[4];
    #pragma unroll
    for (int j = 0; j < 4; ++j) {
        aSrc[j] = X2 + (size_t)(row0 + srow + j * 32) * K2 + skq * 8;
        aDst[j] = As + tid * 8 + j * 2048;
        bDst[j] = Bs + tid * 8 + j * 2048;
    }

    float bestv[16]; int besti[16];
    #pragma unroll
    for (int i = 0; i < 16; ++i) { bestv[i] = FLT_MAX; besti[i] = 0; }

    int aOff[4], bOff[4];
    #pragma unroll
    for (int m = 0; m < 4; ++m) aOff[m] = (wr0 + m * 16 + fl) * 64;
    #pragma unroll
    for (int n = 0; n < 4; ++n) bOff[n] = (wc0 + n * 16 + fl) * 64;
    const int x0 = ((fh) ^ (fl & 7)) * 8;
    const int x1 = ((4 + fh) ^ (fl & 7)) * 8;

    for (int cc = 0; cc < PANELC; cc += 128) {
        const int c0 = cpan + cc;
        const ushort* bSrc[4];
        #pragma unroll
        for (int j = 0; j < 4; ++j)
            bSrc[j] = B2T + (size_t)(c0 + srow + j * 32) * K2 + skq * 8;
        f32x4 acc[4][4];
        #pragma unroll
        for (int m = 0; m < 4; ++m)
            #pragma unroll
            for (int n = 0; n < 4; ++n) acc[m][n] = (f32x4){0.f, 0.f, 0.f, 0.f};

        for (int k0 = 0; k0 < K2; k0 += 64) {
            #pragma unroll
            for (int j = 0; j < 4; ++j) async16(aDst[j], aSrc[j] + k0);
            #pragma unroll
            for (int j = 0; j < 4; ++j) async16(bDst[j], bSrc[j] + k0);
            __syncthreads();
            #pragma unroll
            for (int kk = 0; kk < 2; ++kk) {
                const int xo = kk ? x1 : x0;
                bf16x8 af[4], bfr[4];
                #pragma unroll
                for (int m = 0; m < 4; ++m) af[m] = *(const bf16x8*)&As[aOff[m] + xo];
                #pragma unroll
                for (int n = 0; n < 4; ++n) bfr[n] = *(const bf16x8*)&Bs[bOff[n] + xo];
                #pragma unroll
                for (int m = 0; m < 4; ++m)
                    #pragma unroll
                    for (int n = 0; n < 4; ++n)
                        acc[m][n] = __builtin_amdgcn_mfma_f32_16x16x32_bf16(
                            af[m], bfr[n], acc[m][n], 0, 0, 0);
            }
            __syncthreads();
        }
        #pragma unroll
        for (int n = 0; n < 4; ++n) {
            const int col = c0 + wc0 + n * 16 + fl;
            const float en = enorm[col];
            #pragma unroll
            for (int m = 0; m < 4; ++m)
                #pragma unroll
                for (int r = 0; r < 4; ++r) {
                    const float s = __builtin_fmaf(-2.f, acc[m][n][r], en);
                    const int li = m * 4 + r;
                    if (s < bestv[li]) { bestv[li] = s; besti[li] = col; }
                }
        }
    }

    // cross-lane argmin reduce: rv/ri [32 slots][128 rows]
    __syncthreads();
    float* rv = (float*)smem;
    int* ri = (int*)(smem + 8192);
    const int eidx = (wid & 1) * 16 + fl;
    #pragma unroll
    for (int m = 0; m < 4; ++m)
        #pragma unroll
        for (int r = 0; r < 4; ++r) {
            const int rowl = wr0 + m * 16 + fh * 4 + r;
            rv[eidx * 128 + rowl] = bestv[m * 4 + r];
            ri[eidx * 128 + rowl] = besti[m * 4 + r];
        }
    __syncthreads();
    if (tid < 128) {
        float bv = rv[tid]; int bi = ri[tid];
        #pragma unroll
        for (int e = 1; e < 32; ++e) {
            float v = rv[e * 128 + tid]; int ii = ri[e * 128 + tid];
            if (v < bv || (v == bv && ii < bi)) { bv = v; bi = ii; }
        }
        pv[(size_t)(row0 + tid) * NPAN + blockIdx.y] = bv;
        pi[(size_t)(row0 + tid) * NPAN + blockIdx.y] = bi;
    }
}

// exact f32 re-rank of the 8 panel winners (kills bf16-split tie flips)
__global__ __launch_bounds__(256) void rerank_kernel(
    const float* __restrict__ x, const float* __restrict__ embedT,
    const int* __restrict__ pi, float* __restrict__ out_ind, int* __restrict__ ind_i) {
    const int row = blockIdx.x * 4 + (threadIdx.x >> 6);
    const int lane = threadIdx.x & 63;
    float4 xv = *(const float4*)&x[(size_t)row * DIM + lane * 4];
    float bestd = FLT_MAX; int besti = 0;
    #pragma unroll
    for (int p = 0; p < NPAN; ++p) {           // candidate indices strictly increase with p
        const int c = pi[(size_t)row * NPAN + p];
        float4 e = *(const float4*)&embedT[(size_t)c * DIM + lane * 4];
        float dx = e.x - xv.x, dy = e.y - xv.y, dz = e.z - xv.z, dw = e.w - xv.w;
        float s = dx * dx + dy * dy + dz * dz + dw * dw;
        #pragma unroll
        for (int off = 32; off; off >>= 1) s += __shfl_down(s, off);
        s = __shfl(s, 0);
        if (s < bestd) { bestd = s; besti = c; }
    }
    if (lane == 0) { out_ind[row] = (float)besti; ind_i[row] = besti; }
}

// one wave per row: quantize gather, commit-loss partial, counts, embed_sum scatter
__global__ __launch_bounds__(256) void gather_kernel(
    const float* __restrict__ x, const float* __restrict__ embedT,
    const int* __restrict__ ind, float* __restrict__ q_out,
    float* __restrict__ esumT, float* __restrict__ counts, float* __restrict__ loss_acc) {
    const int row = blockIdx.x * 4 + (threadIdx.x >> 6);
    const int lane = threadIdx.x & 63;
    const int idx = ind[row];
    float4 e  = *(const float4*)&embedT[(size_t)idx * DIM + lane * 4];
    float4 xv = *(const float4*)&x[(size_t)row * DIM + lane * 4];
    *(float4*)&q_out[(size_t)row * DIM + lane * 4] = e;
    float dx = e.x - xv.x, dy = e.y - xv.y, dz = e.z - xv.z, dw = e.w - xv.w;
    float s = dx * dx + dy * dy + dz * dz + dw * dw;
    #pragma unroll
    for (int off = 32; off; off >>= 1) s += __shfl_down(s, off);
    __shared__ float ls[4];
    if (lane == 0) { ls[threadIdx.x >> 6] = s; atomicAdd(&counts[idx], 1.0f); }
    atomicAdd(&esumT[(size_t)idx * DIM + lane * 4 + 0], xv.x);
    atomicAdd(&esumT[(size_t)idx * DIM + lane * 4 + 1], xv.y);
    atomicAdd(&esumT[(size_t)idx * DIM + lane * 4 + 2], xv.z);
    atomicAdd(&esumT[(size_t)idx * DIM + lane * 4 + 3], xv.w);
    __syncthreads();
    if (threadIdx.x == 0) atomicAdd(loss_acc, ls[0] + ls[1] + ls[2] + ls[3]);
}

__global__ void ncs_kernel(const float* __restrict__ cs, const float* __restrict__ counts,
                           float* __restrict__ out_ncs, float* __restrict__ total) {
    int c = blockIdx.x * 256 + threadIdx.x;
    float v = cs[c] * DECAY + counts[c] * OMD;
    out_ncs[c] = v;
    float s = v;
    #pragma unroll
    for (int off = 32; off; off >>= 1) s += __shfl_down(s, off);
    __shared__ float bs[4];
    if ((threadIdx.x & 63) == 0) bs[threadIdx.x >> 6] = s;
    __syncthreads();
    if (threadIdx.x == 0) atomicAdd(total, bs[0] + bs[1] + bs[2] + bs[3]);
}

__global__ void smooth_kernel(const float* __restrict__ out_ncs, const float* __restrict__ total,
                              float* __restrict__ smoothed, const float* __restrict__ loss_acc,
                              float* __restrict__ out_loss) {
    int c = blockIdx.x * 256 + threadIdx.x;
    float tot = *total;
    float v = out_ncs[c];
    smoothed[c] = (v + EPS) / (tot + (float)NE * EPS) * tot;
    if (blockIdx.x == 0 && threadIdx.x == 0)
        *out_loss = *loss_acc * (1.0f / ((float)N_ROWS * (float)DIM));
}

__global__ __launch_bounds__(256) void final_kernel(
    const float* __restrict__ embed_avg, const float* __restrict__ esumT,
    const float* __restrict__ smoothed, float* __restrict__ out_ne,
    float* __restrict__ out_nea) {
    __shared__ float t[32][33];
    int c0 = blockIdx.x * 32, d0 = blockIdx.y * 32;
    int tx = threadIdx.x & 31, ty = threadIdx.x >> 5;
    #pragma unroll
    for (int r = 0; r < 4; ++r)
        t[ty + r * 8][tx] = esumT[(size_t)(c0 + ty + r * 8) * DIM + d0 + tx];
    __syncthreads();
    #pragma unroll
    for (int r = 0; r < 4; ++r) {
        int d = d0 + ty + r * 8, c = c0 + tx;
        float es = t[tx][ty + r * 8];
        float ea = embed_avg[(size_t)d * NE + c] * DECAY + es * OMD;
        out_nea[(size_t)d * NE + c] = ea;
        out_ne[(size_t)d * NE + c] = ea / smoothed[c];
    }
}

extern "C" void kernel_launch(void* const* d_in, const int* in_sizes, int n_in,
                              void* d_out, int out_size, void* d_ws, size_t ws_size,
                              hipStream_t stream) {
    const float* input     = (const float*)d_in[0];
    const float* embed     = (const float*)d_in[1];
    const float* cs        = (const float*)d_in[2];
    const float* embed_avg = (const float*)d_in[3];
    float* out = (float*)d_out;
    float* ws  = (float*)d_ws;

    hipMemsetAsync(ws + WS_COUNTS, 0, (size_t)8192 * 4, stream);
    hipMemsetAsync(ws + WS_LOSS, 0, (size_t)2 * 4, stream);

    convx_kernel<<<4096, 256, 0, stream>>>(input, (ushort*)(ws + WS_X2));
    convE_kernel<<<dim3(256, 8), 256, 0, stream>>>(embed, (ushort*)(ws + WS_B2T));
    enorm_kernel<<<32, 256, 0, stream>>>(embed, ws + WS_ENORM);
    argmin_mfma<<<dim3(128, 8), 256, 0, stream>>>(
        (const ushort*)(ws + WS_X2), (const ushort*)(ws + WS_B2T), ws + WS_ENORM,
        ws + WS_PV, (int*)(ws + WS_PI));
    // X2 region is dead from here on -> overlay embedT / esumT
    transpose_kernel<<<dim3(256, 8), 256, 0, stream>>>(embed, ws + WS_EMBEDT);
    hipMemsetAsync(ws + WS_ESUMT, 0, (size_t)2097152 * 4, stream);
    rerank_kernel<<<4096, 256, 0, stream>>>(input, ws + WS_EMBEDT, (int*)(ws + WS_PI),
                                            out + OUT_IND, (int*)(ws + WS_INDI));
    gather_kernel<<<4096, 256, 0, stream>>>(input, ws + WS_EMBEDT, (int*)(ws + WS_INDI),
                                            out + OUT_Q, ws + WS_ESUMT,
                                            ws + WS_COUNTS, ws + WS_LOSS);
    ncs_kernel<<<32, 256, 0, stream>>>(cs, ws + WS_COUNTS, out + OUT_NCS, ws + WS_TOTAL);
    smooth_kernel<<<32, 256, 0, stream>>>(out + OUT_NCS, ws + WS_TOTAL, ws + WS_SMOOTH,
                                          ws + WS_LOSS, out + OUT_LOSS);
    final_kernel<<<dim3(256, 8), 256, 0, stream>>>(embed_avg, ws + WS_ESUMT, ws + WS_SMOOTH,
                                                   out + OUT_NE, out + OUT_NEA);
}